// Round 1
// baseline (821.838 us; speedup 1.0000x reference)
//
#include <hip/hip_runtime.h>
#include <hip/hip_bf16.h>
#include <stdint.h>

// Problem constants
#define NB   4096   // batch
#define NTOK 16     // tokens
#define ND   256    // token dim
#define NS   256    // state size
#define NL   4      // layers
#define KIN  1056   // stoch(1024) + action(32)
#define RMS_EPS 1e-4f

typedef float f32x4 __attribute__((ext_vector_type(4)));
typedef short s16x8 __attribute__((ext_vector_type(8)));

__device__ __forceinline__ unsigned short f2bf(float f) {
    unsigned u = __float_as_uint(f);
    u += 0x7fff + ((u >> 16) & 1);          // round-to-nearest-even
    return (unsigned short)(u >> 16);
}
__device__ __forceinline__ float bf2f(unsigned short h) {
    return __uint_as_float((unsigned)h << 16);
}

// ---------------- prep kernels ----------------

__global__ __launch_bounds__(256) void k_cast(const float* __restrict__ src,
                                              unsigned short* __restrict__ dst, int n) {
    for (int i = blockIdx.x * blockDim.x + threadIdx.x; i < n; i += gridDim.x * blockDim.x)
        dst[i] = f2bf(src[i]);
}

// A0[b][k] = k<1024 ? stoch[b][k] : action_norm[b][k-1024]   (bf16)
__global__ __launch_bounds__(256) void k_build_a0(const float* __restrict__ stoch,
                                                  const float* __restrict__ act,
                                                  unsigned short* __restrict__ a0) {
    int total = NB * KIN;
    for (int i = blockIdx.x * blockDim.x + threadIdx.x; i < total; i += gridDim.x * blockDim.x) {
        int b = i / KIN, k = i - b * KIN;
        float v;
        if (k < 1024) v = stoch[b * 1024 + k];
        else { float a = act[b * 32 + (k - 1024)]; v = a / fmaxf(fabsf(a), 1.0f); }
        a0[i] = f2bf(v);
    }
}

// tok[b][0..14][:] = deter[b][1..15][:]  (float4 units: 960 per row)
__global__ __launch_bounds__(256) void k_shift(const float4* __restrict__ deter4,
                                               float4* __restrict__ tok4) {
    int total = NB * 960;
    for (int i = blockIdx.x * blockDim.x + threadIdx.x; i < total; i += gridDim.x * blockDim.x) {
        int b = i / 960, r = i - b * 960;
        tok4[(size_t)b * 1024 + r] = deter4[(size_t)b * 1024 + 64 + r];
    }
}

// ---------------- GEMM cores ----------------
// All GEMMs: out[m][n] = sum_k A[m][k] * W[n][k]   (W stored [N][K] row-major)
// Block: 256 threads = 4 waves (2m x 2n). Block tile 128m x 64n, wave tile 64m x 32n.
// mfma_f32_16x16x32_bf16 layouts:
//   a_frag lane l elem e = A[m0 + (l&15)][k0 + (l>>4)*8 + e]
//   b_frag lane l elem e = W[n0 + (l&15)][k0 + (l>>4)*8 + e]
//   d      lane l reg  r = D[(l>>4)*4 + r][l&15]

#define KR 264   // padded LDS row (256 + 8 elems); 528B row stride (16B-aligned, 2-way banks)

// Stage W rows [n0, n0+64) x K=256 into LDS (per-thread 64 contiguous elems)
__device__ __forceinline__ void stage_w(const unsigned short* __restrict__ W, int n0,
                                        unsigned short* lds) {
    int t = threadIdx.x;
    int row = t >> 2, kc = (t & 3) * 64;
    const unsigned short* src = &W[(size_t)(n0 + row) * 256 + kc];
    unsigned short* dst = &lds[row * KR + kc];
#pragma unroll
    for (int j = 0; j < 8; j++)
        *reinterpret_cast<s16x8*>(dst + j * 8) = *reinterpret_cast<const s16x8*>(src + j * 8);
}

// K=256 resident-W accumulate pass
__device__ __forceinline__ void gemm_res(const unsigned short* __restrict__ A,
                                         const unsigned short* lds, int m0,
                                         f32x4 acc[4][2]) {
    const int lane = threadIdx.x & 63;
    const int wvid = threadIdx.x >> 6;
    const int wm = wvid & 1, wn = wvid >> 1;
    const int mbase = m0 + wm * 64 + (lane & 15);
    const int koff = (lane >> 4) * 8;
    const int brow = wn * 32 + (lane & 15);
#pragma unroll
    for (int kc = 0; kc < 256; kc += 32) {
        s16x8 a[4];
#pragma unroll
        for (int mf = 0; mf < 4; mf++)
            a[mf] = *reinterpret_cast<const s16x8*>(&A[(size_t)(mbase + mf * 16) * 256 + kc + koff]);
#pragma unroll
        for (int nf = 0; nf < 2; nf++) {
            s16x8 bfr = *reinterpret_cast<const s16x8*>(&lds[(brow + nf * 16) * KR + kc + koff]);
#pragma unroll
            for (int mf = 0; mf < 4; mf++)
                acc[mf][nf] = __builtin_amdgcn_mfma_f32_16x16x32_bf16(a[mf], bfr, acc[mf][nf], 0, 0, 0);
        }
    }
}

// Chunked-K pass (for K=1056 input GEMM): stage 64n x 32k per chunk
#define KP 40    // 32 + 8 pad elems; 80B row stride
__device__ __forceinline__ void gemm_chunked(const unsigned short* __restrict__ A,
                                             const unsigned short* __restrict__ W,
                                             int K, int m0, int n0,
                                             unsigned short* lds, f32x4 acc[4][2]) {
    const int tid = threadIdx.x;
    const int lane = tid & 63;
    const int wvid = tid >> 6;
    const int wm = wvid & 1, wn = wvid >> 1;
    const int srow = tid >> 2, skk = (tid & 3) * 8;
    const int mbase = m0 + wm * 64 + (lane & 15);
    const int koff = (lane >> 4) * 8;
    const int brow = wn * 32 + (lane & 15);
    for (int kc = 0; kc < K; kc += 32) {
        __syncthreads();
        *reinterpret_cast<s16x8*>(&lds[srow * KP + skk]) =
            *reinterpret_cast<const s16x8*>(&W[(size_t)(n0 + srow) * K + kc + skk]);
        __syncthreads();
        s16x8 a[4];
#pragma unroll
        for (int mf = 0; mf < 4; mf++)
            a[mf] = *reinterpret_cast<const s16x8*>(&A[(size_t)(mbase + mf * 16) * K + kc + koff]);
#pragma unroll
        for (int nf = 0; nf < 2; nf++) {
            s16x8 bfr = *reinterpret_cast<const s16x8*>(&lds[(brow + nf * 16) * KP + koff]);
#pragma unroll
            for (int mf = 0; mf < 4; mf++)
                acc[mf][nf] = __builtin_amdgcn_mfma_f32_16x16x32_bf16(a[mf], bfr, acc[mf][nf], 0, 0, 0);
        }
    }
}

__device__ __forceinline__ void zero_acc(f32x4 acc[4][2]) {
#pragma unroll
    for (int i = 0; i < 4; i++)
#pragma unroll
        for (int j = 0; j < 2; j++)
            acc[i][j] = (f32x4){0.f, 0.f, 0.f, 0.f};
}

// ---------------- GEMM kernels ----------------

// h = A0 @ W0^T + b0   (fp32 out, M=4096, K=1056)
__global__ __launch_bounds__(256) void k_gemm_h(const unsigned short* __restrict__ A0,
                                                const unsigned short* __restrict__ W0bf,
                                                const float* __restrict__ b0,
                                                float* __restrict__ h) {
    __shared__ unsigned short lds[64 * KP];
    f32x4 acc[4][2];
    zero_acc(acc);
    int m0 = blockIdx.x * 128, n0 = blockIdx.y * 64;
    gemm_chunked(A0, W0bf, KIN, m0, n0, lds, acc);
    int lane = threadIdx.x & 63, wvid = threadIdx.x >> 6;
    int wm = wvid & 1, wn = wvid >> 1;
    int rbase = m0 + wm * 64 + (lane >> 4) * 4;
    int cbase = n0 + wn * 32 + (lane & 15);
#pragma unroll
    for (int mf = 0; mf < 4; mf++)
#pragma unroll
        for (int nf = 0; nf < 2; nf++) {
            int col = cbase + nf * 16;
            float bb = b0[col];
#pragma unroll
            for (int r = 0; r < 4; r++)
                h[(size_t)(rbase + mf * 16 + r) * ND + col] = acc[mf][nf][r] + bb;
        }
}

// u = x @ Win^T + b_in  (bf16 out, M=65536, K=256)
__global__ __launch_bounds__(256) void k_gemm_u(const unsigned short* __restrict__ A,
                                                const unsigned short* __restrict__ W,
                                                const float* __restrict__ bias,
                                                unsigned short* __restrict__ u) {
    __shared__ unsigned short lds[64 * KR];
    int m0 = blockIdx.x * 128, n0 = blockIdx.y * 64;
    stage_w(W, n0, lds);
    f32x4 acc[4][2];
    zero_acc(acc);
    __syncthreads();
    gemm_res(A, lds, m0, acc);
    int lane = threadIdx.x & 63, wvid = threadIdx.x >> 6;
    int wm = wvid & 1, wn = wvid >> 1;
    int rbase = m0 + wm * 64 + (lane >> 4) * 4;
    int cbase = n0 + wn * 32 + (lane & 15);
#pragma unroll
    for (int mf = 0; mf < 4; mf++)
#pragma unroll
        for (int nf = 0; nf < 2; nf++) {
            int col = cbase + nf * 16;
            float bb = bias[col];
#pragma unroll
            for (int r = 0; r < 4; r++)
                u[(size_t)(rbase + mf * 16 + r) * NS + col] = f2bf(acc[mf][nf][r] + bb);
        }
}

// tok += states @ Wout^T + x @ Wskip^T + b_out + b_skip   (fp32 in/out, M=65536)
__global__ __launch_bounds__(256) void k_gemm_out(const unsigned short* __restrict__ st,
                                                  const unsigned short* __restrict__ x,
                                                  const unsigned short* __restrict__ Wout,
                                                  const unsigned short* __restrict__ Wskip,
                                                  const float* __restrict__ bout,
                                                  const float* __restrict__ bskip,
                                                  float* __restrict__ tok) {
    __shared__ unsigned short lds[2 * 64 * KR];   // 67.6 KB -> 2 blocks/CU
    int m0 = blockIdx.x * 128, n0 = blockIdx.y * 64;
    stage_w(Wout, n0, lds);
    stage_w(Wskip, n0, lds + 64 * KR);
    f32x4 acc[4][2];
    zero_acc(acc);
    __syncthreads();
    gemm_res(st, lds, m0, acc);
    gemm_res(x, lds + 64 * KR, m0, acc);
    int lane = threadIdx.x & 63, wvid = threadIdx.x >> 6;
    int wm = wvid & 1, wn = wvid >> 1;
    int rbase = m0 + wm * 64 + (lane >> 4) * 4;
    int cbase = n0 + wn * 32 + (lane & 15);
#pragma unroll
    for (int mf = 0; mf < 4; mf++)
#pragma unroll
        for (int nf = 0; nf < 2; nf++) {
            int col = cbase + nf * 16;
            float bb = bout[col] + bskip[col];
#pragma unroll
            for (int r = 0; r < 4; r++) {
                size_t idx = (size_t)(rbase + mf * 16 + r) * ND + col;
                tok[idx] = tok[idx] + acc[mf][nf][r] + bb;
            }
        }
}

// ---------------- rmsnorm (one wave per 256-elem row) ----------------
// MODE 0: out bf16 (x buffer)   MODE 1: out fp32 (final output)
// MODE 2: +SiLU, out fp32 strided into tok[:,15,:]  (h -> new_tok)
template <int MODE>
__global__ __launch_bounds__(256) void k_rms(const float* __restrict__ X,
                                             const float* __restrict__ w,
                                             void* __restrict__ Y, int rows) {
    int row = blockIdx.x * 4 + (threadIdx.x >> 6);
    int lane = threadIdx.x & 63;
    if (row >= rows) return;
    float4 v = reinterpret_cast<const float4*>(X)[(size_t)row * 64 + lane];
    float ss = v.x * v.x + v.y * v.y + v.z * v.z + v.w * v.w;
#pragma unroll
    for (int off = 32; off > 0; off >>= 1) ss += __shfl_xor(ss, off);
    float scale = rsqrtf(ss * (1.0f / 256.0f) + RMS_EPS);
    float4 wv = reinterpret_cast<const float4*>(w)[lane];
    float o0 = v.x * scale * wv.x, o1 = v.y * scale * wv.y;
    float o2 = v.z * scale * wv.z, o3 = v.w * scale * wv.w;
    if (MODE == 0) {
        ushort4 p;
        p.x = f2bf(o0); p.y = f2bf(o1); p.z = f2bf(o2); p.w = f2bf(o3);
        reinterpret_cast<ushort4*>(Y)[(size_t)row * 64 + lane] = p;
    } else if (MODE == 1) {
        reinterpret_cast<float4*>(Y)[(size_t)row * 64 + lane] = make_float4(o0, o1, o2, o3);
    } else {
        float4 q;
        q.x = o0 / (1.f + expf(-o0));
        q.y = o1 / (1.f + expf(-o1));
        q.z = o2 / (1.f + expf(-o2));
        q.w = o3 / (1.f + expf(-o3));
        float* yp = (float*)Y + (size_t)row * (NTOK * ND) + 15 * ND;   // tok[b][15][:]
        reinterpret_cast<float4*>(yp)[lane] = q;
    }
}

// ---------------- decay scan (in-place on u, bf16) ----------------
// thread handles (b, 8 consecutive s); states[t] = decay*states[t-1] + u[t]
__global__ __launch_bounds__(256) void k_scan(unsigned short* __restrict__ u,
                                              const float* __restrict__ ld) {
    int i = blockIdx.x * blockDim.x + threadIdx.x;   // NB*32 total
    int b = i >> 5, s8 = (i & 31) * 8;
    float dec[8], stt[8];
#pragma unroll
    for (int j = 0; j < 8; j++) {
        dec[j] = 1.f / (1.f + expf(-ld[s8 + j]));
        stt[j] = 0.f;
    }
    size_t base = (size_t)b * (NTOK * NS) + s8;
    for (int t = 0; t < NTOK; t++) {
        s16x8 uv = *reinterpret_cast<s16x8*>(&u[base + t * NS]);
        s16x8 sv;
#pragma unroll
        for (int j = 0; j < 8; j++) {
            stt[j] = dec[j] * stt[j] + bf2f((unsigned short)uv[j]);
            sv[j] = (short)f2bf(stt[j]);
        }
        *reinterpret_cast<s16x8*>(&u[base + t * NS]) = sv;
    }
}

// ---------------- launch ----------------

extern "C" void kernel_launch(void* const* d_in, const int* in_sizes, int n_in,
                              void* d_out, int out_size, void* d_ws, size_t ws_size,
                              hipStream_t stream) {
    const float* stoch   = (const float*)d_in[0];
    const float* deter   = (const float*)d_in[1];
    const float* action  = (const float*)d_in[2];
    const float* W0      = (const float*)d_in[3];
    const float* b0      = (const float*)d_in[4];
    const float* g0      = (const float*)d_in[5];
    const float* norm_w  = (const float*)d_in[6];
    const float* W_in    = (const float*)d_in[7];
    const float* b_in    = (const float*)d_in[8];
    const float* W_out   = (const float*)d_in[9];
    const float* b_out   = (const float*)d_in[10];
    const float* W_skip  = (const float*)d_in[11];
    const float* b_skip  = (const float*)d_in[12];
    const float* log_dec = (const float*)d_in[13];
    const float* onw     = (const float*)d_in[14];
    float* out = (float*)d_out;

    // workspace carve (all 16B-aligned)
    unsigned short* A0bf    = (unsigned short*)d_ws;                  // NB*KIN
    unsigned short* W0bf    = A0bf + (size_t)NB * KIN;                // 256*KIN
    unsigned short* Winbf   = W0bf + (size_t)256 * KIN;               // NL*256*256
    unsigned short* Woutbf  = Winbf + (size_t)NL * 256 * 256;
    unsigned short* Wskipbf = Woutbf + (size_t)NL * 256 * 256;
    unsigned short* xbf     = Wskipbf + (size_t)NL * 256 * 256;       // NB*NTOK*ND
    unsigned short* ubf     = xbf + (size_t)NB * NTOK * ND;           // NB*NTOK*NS (scan in-place)
    float* tok  = (float*)(ubf + (size_t)NB * NTOK * ND);             // NB*NTOK*ND fp32
    float* hbuf = tok + (size_t)NB * NTOK * ND;                       // NB*ND fp32

    const int MROWS = NB * NTOK;   // 65536

    // prep
    k_cast<<<512, 256, 0, stream>>>(W0, W0bf, 256 * KIN);
    k_cast<<<512, 256, 0, stream>>>(W_in, Winbf, NL * 256 * 256);
    k_cast<<<512, 256, 0, stream>>>(W_out, Woutbf, NL * 256 * 256);
    k_cast<<<512, 256, 0, stream>>>(W_skip, Wskipbf, NL * 256 * 256);
    k_build_a0<<<2048, 256, 0, stream>>>(stoch, action, A0bf);
    k_shift<<<2048, 256, 0, stream>>>((const float4*)deter, (float4*)tok);

    // input proj -> rmsnorm -> silu -> tok[:,15,:]
    k_gemm_h<<<dim3(NB / 128, 4), 256, 0, stream>>>(A0bf, W0bf, b0, hbuf);
    k_rms<2><<<NB / 4, 256, 0, stream>>>(hbuf, g0, (void*)tok, NB);

    // layers
    for (int l = 0; l < NL; l++) {
        k_rms<0><<<MROWS / 4, 256, 0, stream>>>(tok, norm_w + l * 256, (void*)xbf, MROWS);
        k_gemm_u<<<dim3(MROWS / 128, 4), 256, 0, stream>>>(xbf, Winbf + (size_t)l * 65536,
                                                           b_in + l * 256, ubf);
        k_scan<<<NB * 32 / 256, 256, 0, stream>>>(ubf, log_dec + l * 256);
        k_gemm_out<<<dim3(MROWS / 128, 4), 256, 0, stream>>>(ubf, xbf,
                                                             Woutbf + (size_t)l * 65536,
                                                             Wskipbf + (size_t)l * 65536,
                                                             b_out + l * 256, b_skip + l * 256, tok);
    }

    // final rmsnorm -> fp32 output
    k_rms<1><<<MROWS / 4, 256, 0, stream>>>(tok, onw, (void*)out, MROWS);
}

// Round 4
// 392.472 us; speedup vs baseline: 2.0940x; 2.0940x over previous
//
#include <hip/hip_runtime.h>
#include <hip/hip_bf16.h>
#include <stdint.h>

#define NB   4096
#define NTOK 16
#define ND   256
#define NS   256
#define NL   4
#define KIN  1056
#define RMS_EPS 1e-4f

typedef float f32x4 __attribute__((ext_vector_type(4)));
typedef short s16x8 __attribute__((ext_vector_type(8)));

__device__ __forceinline__ unsigned short f2bf(float f) {
    unsigned u = __float_as_uint(f);
    u += 0x7fff + ((u >> 16) & 1);          // RNE
    return (unsigned short)(u >> 16);
}

// ---------------- prep kernels ----------------

__global__ __launch_bounds__(256) void k_cast(const float* __restrict__ src,
                                              unsigned short* __restrict__ dst, int n) {
    for (int i = blockIdx.x * blockDim.x + threadIdx.x; i < n; i += gridDim.x * blockDim.x)
        dst[i] = f2bf(src[i]);
}

__global__ __launch_bounds__(256) void k_build_a0(const float* __restrict__ stoch,
                                                  const float* __restrict__ act,
                                                  unsigned short* __restrict__ a0) {
    int total = NB * KIN;
    for (int i = blockIdx.x * blockDim.x + threadIdx.x; i < total; i += gridDim.x * blockDim.x) {
        int b = i / KIN, k = i - b * KIN;
        float v;
        if (k < 1024) v = stoch[b * 1024 + k];
        else { float a = act[b * 32 + (k - 1024)]; v = a / fmaxf(fabsf(a), 1.0f); }
        a0[i] = f2bf(v);
    }
}

// ---------------- input-proj GEMM (K=1056) ----------------
#define KP 40
__device__ __forceinline__ void gemm_chunked(const unsigned short* __restrict__ A,
                                             const unsigned short* __restrict__ W,
                                             int K, int m0, int n0,
                                             unsigned short* lds, f32x4 acc[4][2]) {
    const int tid = threadIdx.x;
    const int lane = tid & 63;
    const int wvid = tid >> 6;
    const int wm = wvid & 1, wn = wvid >> 1;
    const int srow = tid >> 2, skk = (tid & 3) * 8;
    const int mbase = m0 + wm * 64 + (lane & 15);
    const int koff = (lane >> 4) * 8;
    const int brow = wn * 32 + (lane & 15);
    for (int kc = 0; kc < K; kc += 32) {
        __syncthreads();
        *reinterpret_cast<s16x8*>(&lds[srow * KP + skk]) =
            *reinterpret_cast<const s16x8*>(&W[(size_t)(n0 + srow) * K + kc + skk]);
        __syncthreads();
        s16x8 a[4];
#pragma unroll
        for (int mf = 0; mf < 4; mf++)
            a[mf] = *reinterpret_cast<const s16x8*>(&A[(size_t)(mbase + mf * 16) * K + kc + koff]);
#pragma unroll
        for (int nf = 0; nf < 2; nf++) {
            s16x8 bfr = *reinterpret_cast<const s16x8*>(&lds[(brow + nf * 16) * KP + koff]);
#pragma unroll
            for (int mf = 0; mf < 4; mf++)
                acc[mf][nf] = __builtin_amdgcn_mfma_f32_16x16x32_bf16(a[mf], bfr, acc[mf][nf], 0, 0, 0);
        }
    }
}

__global__ __launch_bounds__(256) void k_gemm_h(const unsigned short* __restrict__ A0,
                                                const unsigned short* __restrict__ W0bf,
                                                const float* __restrict__ b0,
                                                float* __restrict__ h) {
    __shared__ unsigned short lds[64 * KP];
    f32x4 acc[4][2];
#pragma unroll
    for (int i = 0; i < 4; i++)
#pragma unroll
        for (int j = 0; j < 2; j++) acc[i][j] = (f32x4){0.f, 0.f, 0.f, 0.f};
    int m0 = blockIdx.x * 128, n0 = blockIdx.y * 64;
    gemm_chunked(A0, W0bf, KIN, m0, n0, lds, acc);
    int lane = threadIdx.x & 63, wvid = threadIdx.x >> 6;
    int wm = wvid & 1, wn = wvid >> 1;
    int rbase = m0 + wm * 64 + (lane >> 4) * 4;
    int cbase = n0 + wn * 32 + (lane & 15);
#pragma unroll
    for (int mf = 0; mf < 4; mf++)
#pragma unroll
        for (int nf = 0; nf < 2; nf++) {
            int col = cbase + nf * 16;
            float bb = b0[col];
#pragma unroll
            for (int r = 0; r < 4; r++)
                h[(size_t)(rbase + mf * 16 + r) * ND + col] = acc[mf][nf][r] + bb;
        }
}

// rms + silu -> ntok (contiguous fp32 [4096][256])
__global__ __launch_bounds__(256) void k_h_norm(const float* __restrict__ X,
                                                const float* __restrict__ wg,
                                                float* __restrict__ ntok) {
    int row = blockIdx.x * 4 + (threadIdx.x >> 6);
    int lane = threadIdx.x & 63;
    float4 v = reinterpret_cast<const float4*>(X)[(size_t)row * 64 + lane];
    float ss = v.x * v.x + v.y * v.y + v.z * v.z + v.w * v.w;
#pragma unroll
    for (int off = 32; off > 0; off >>= 1) ss += __shfl_xor(ss, off);
    float scale = rsqrtf(ss * (1.0f / 256.0f) + RMS_EPS);
    float4 wv = reinterpret_cast<const float4*>(wg)[lane];
    float o0 = v.x * scale * wv.x, o1 = v.y * scale * wv.y;
    float o2 = v.z * scale * wv.z, o3 = v.w * scale * wv.w;
    float4 q;
    q.x = o0 / (1.f + expf(-o0));
    q.y = o1 / (1.f + expf(-o1));
    q.z = o2 / (1.f + expf(-o2));
    q.w = o3 / (1.f + expf(-o3));
    reinterpret_cast<float4*>(ntok)[(size_t)row * 64 + lane] = q;
}

// ---------------- persistent mega-kernel ----------------
// Block: 256 thr = 4 waves. Owns 4 batch rows -> M = 64 token-rows, all 4 layers.
// tok fp32 resident in regs, D-layout: wave w holds cols [w*64,(w+1)*64);
//   tok[mf][nf][r] = tok_row(mf*16 + (lane>>4)*4 + r), col(w*64 + nf*16 + (lane&15))
// x, st staged bf16 in LDS [64][264] (row stride 264 elems -> conflict-free b128 frags).
// Scan done fully in-register: t-groups == lane>>4 groups; group-prefix via __shfl.

#define LSTR 264

__device__ __forceinline__ void gemm_pass(const unsigned short* lds_a,
                                          const unsigned short* __restrict__ B,
                                          int w, int q, int g, f32x4 acc[4][4]) {
    const unsigned short* bp = B + (size_t)(w * 64 + q) * 256 + g * 8;
    const unsigned short* ap = lds_a + q * LSTR + g * 8;
#pragma unroll 2
    for (int kc = 0; kc < 256; kc += 32) {
        s16x8 bw[4];
#pragma unroll
        for (int nf = 0; nf < 4; nf++)
            bw[nf] = *reinterpret_cast<const s16x8*>(bp + nf * (16 * 256) + kc);
#pragma unroll
        for (int mf = 0; mf < 4; mf++) {
            s16x8 a = *reinterpret_cast<const s16x8*>(ap + mf * (16 * LSTR) + kc);
#pragma unroll
            for (int nf = 0; nf < 4; nf++)
                acc[mf][nf] = __builtin_amdgcn_mfma_f32_16x16x32_bf16(a, bw[nf], acc[mf][nf], 0, 0, 0);
        }
    }
}

__global__ __launch_bounds__(256, 2) void k_mega(
    const float* __restrict__ deter, const float* __restrict__ ntok,
    const unsigned short* __restrict__ Win, const unsigned short* __restrict__ Wout,
    const unsigned short* __restrict__ Wskip,
    const float* __restrict__ norm_w, const float* __restrict__ b_in,
    const float* __restrict__ b_out, const float* __restrict__ b_skip,
    const float* __restrict__ log_dec, const float* __restrict__ out_nw,
    float* __restrict__ out)
{
    __shared__ __align__(16) unsigned short xs[64 * LSTR];
    __shared__ __align__(16) unsigned short st[64 * LSTR];
    __shared__ __align__(16) float red[4 * 64 + 64];

    const int tid = threadIdx.x;
    const int lane = tid & 63;
    const int w = tid >> 6;
    const int g = lane >> 4;
    const int q = lane & 15;
    const int e = lane & 1;
    const int b0 = blockIdx.x * 4;
    const int lm16 = (lane - 16) & 63, lm32 = (lane - 32) & 63, lm48 = (lane - 48) & 63;

    f32x4 tok[4][4];
    // ---- entry: shifted deter tokens + new token ----
#pragma unroll
    for (int mf = 0; mf < 4; mf++) {
        const float* dbase = deter + (size_t)(b0 + mf) * 4096;
        const float* nbase = ntok + (size_t)(b0 + mf) * 256;
#pragma unroll
        for (int nf = 0; nf < 4; nf++) {
            int col = w * 64 + nf * 16 + q;
#pragma unroll
            for (int r = 0; r < 4; r++) {
                int t = g * 4 + r;
                tok[mf][nf][r] = (t < 15) ? dbase[(t + 1) * 256 + col] : nbase[col];
            }
        }
    }

    float scale[4][4];

    auto rms_scale = [&]() {
#pragma unroll
        for (int mf = 0; mf < 4; mf++) {
            f32x4 p = (f32x4){0.f, 0.f, 0.f, 0.f};
#pragma unroll
            for (int nf = 0; nf < 4; nf++)
#pragma unroll
                for (int r = 0; r < 4; r++) p[r] += tok[mf][nf][r] * tok[mf][nf][r];
#pragma unroll
            for (int mask = 1; mask < 16; mask <<= 1) {
#pragma unroll
                for (int r = 0; r < 4; r++) p[r] += __shfl_xor(p[r], mask);
            }
            if (q == 0) *reinterpret_cast<f32x4*>(&red[w * 64 + mf * 16 + g * 4]) = p;
        }
        __syncthreads();
        if (tid < 64) {
            float s = red[tid] + red[64 + tid] + red[128 + tid] + red[192 + tid];
            red[256 + tid] = rsqrtf(s * (1.0f / 256.0f) + RMS_EPS);
        }
        __syncthreads();
#pragma unroll
        for (int mf = 0; mf < 4; mf++) {
            f32x4 sc = *reinterpret_cast<const f32x4*>(&red[256 + mf * 16 + g * 4]);
#pragma unroll
            for (int r = 0; r < 4; r++) scale[mf][r] = sc[r];
        }
    };

    // pack-pair bf16 scatter into [m][264] LDS (D-layout -> A-layout transpose)
    auto scat = [&](unsigned short* dst, float vE, float vO, int mf, int r, int nf2) {
        float oE = __shfl_xor(vE, 1);
        float oO = __shfl_xor(vO, 1);
        float lo = e ? oO : vE;
        float hi = e ? vO : oE;
        unsigned pk = (unsigned)f2bf(lo) | ((unsigned)f2bf(hi) << 16);
        int m = mf * 16 + g * 4 + r;
        int colb = w * 64 + (nf2 * 2 + e) * 16 + (q & ~1);
        *reinterpret_cast<unsigned*>(&dst[m * LSTR + colb]) = pk;
    };

    for (int l = 0; l < NL; l++) {
        const unsigned short* Wi = Win + (size_t)l * 65536;
        const unsigned short* Wo = Wout + (size_t)l * 65536;
        const unsigned short* Ws = Wskip + (size_t)l * 65536;
        float nw[4], bi[4], dec[4], bo[4];
#pragma unroll
        for (int nf = 0; nf < 4; nf++) {
            int col = w * 64 + nf * 16 + q;
            nw[nf] = norm_w[l * 256 + col];
            bi[nf] = b_in[l * 256 + col];
            dec[nf] = 1.f / (1.f + expf(-log_dec[l * 256 + col]));
            bo[nf] = b_out[l * 256 + col] + b_skip[l * 256 + col];
        }

        rms_scale();
        // x = rms(tok)*nw -> LDS
#pragma unroll
        for (int mf = 0; mf < 4; mf++)
#pragma unroll
            for (int r = 0; r < 4; r++)
#pragma unroll
                for (int nf2 = 0; nf2 < 2; nf2++) {
                    float vE = tok[mf][nf2 * 2][r] * scale[mf][r] * nw[nf2 * 2];
                    float vO = tok[mf][nf2 * 2 + 1][r] * scale[mf][r] * nw[nf2 * 2 + 1];
                    scat(xs, vE, vO, mf, r, nf2);
                }
        __syncthreads();

        // u = x @ Win^T  (fp32 acc)
        f32x4 acc[4][4];
#pragma unroll
        for (int i = 0; i < 4; i++)
#pragma unroll
            for (int j = 0; j < 4; j++) acc[i][j] = (f32x4){0.f, 0.f, 0.f, 0.f};
        gemm_pass(xs, Wi, w, q, g, acc);

        // bias + in-register decay scan over t (= g*4 + r within batch row mf)
#pragma unroll
        for (int mf = 0; mf < 4; mf++)
#pragma unroll
            for (int nf = 0; nf < 4; nf++) {
                float d1 = dec[nf], dd2 = d1 * d1, dd3 = dd2 * d1, dd4 = dd2 * dd2, dd8 = dd4 * dd4;
                f32x4& u = acc[mf][nf];
                float s0 = u[0] + bi[nf];
                float s1 = u[1] + bi[nf] + d1 * s0;
                float s2 = u[2] + bi[nf] + d1 * s1;
                float s3 = u[3] + bi[nf] + d1 * s2;
                float Q = s3;
                float q1 = __shfl(Q, lm16); q1 = (g >= 1) ? q1 : 0.f;
                float q2 = __shfl(Q, lm32); q2 = (g >= 2) ? q2 : 0.f;
                float q3 = __shfl(Q, lm48); q3 = (g >= 3) ? q3 : 0.f;
                float carry = q1 + dd4 * q2 + dd8 * q3;
                u[0] = s0 + d1 * carry;
                u[1] = s1 + dd2 * carry;
                u[2] = s2 + dd3 * carry;
                u[3] = s3 + dd4 * carry;
            }

        // st -> LDS
#pragma unroll
        for (int mf = 0; mf < 4; mf++)
#pragma unroll
            for (int r = 0; r < 4; r++)
#pragma unroll
                for (int nf2 = 0; nf2 < 2; nf2++)
                    scat(st, acc[mf][nf2 * 2][r], acc[mf][nf2 * 2 + 1][r], mf, r, nf2);
        __syncthreads();

        // tok += st @ Wout^T + x @ Wskip^T + biases
#pragma unroll
        for (int i = 0; i < 4; i++)
#pragma unroll
            for (int j = 0; j < 4; j++) acc[i][j] = (f32x4){0.f, 0.f, 0.f, 0.f};
        gemm_pass(st, Wo, w, q, g, acc);
        gemm_pass(xs, Ws, w, q, g, acc);
#pragma unroll
        for (int mf = 0; mf < 4; mf++)
#pragma unroll
            for (int nf = 0; nf < 4; nf++)
#pragma unroll
                for (int r = 0; r < 4; r++)
                    tok[mf][nf][r] += acc[mf][nf][r] + bo[nf];
    }

    // final rmsnorm -> fp32 out (packed float2 stores)
    rms_scale();
    float onw[4];
#pragma unroll
    for (int nf = 0; nf < 4; nf++) onw[nf] = out_nw[w * 64 + nf * 16 + q];
#pragma unroll
    for (int mf = 0; mf < 4; mf++) {
        float* obase = out + (size_t)(b0 + mf) * 4096;
#pragma unroll
        for (int r = 0; r < 4; r++)
#pragma unroll
            for (int nf2 = 0; nf2 < 2; nf2++) {
                float vE = tok[mf][nf2 * 2][r] * scale[mf][r] * onw[nf2 * 2];
                float vO = tok[mf][nf2 * 2 + 1][r] * scale[mf][r] * onw[nf2 * 2 + 1];
                float oE = __shfl_xor(vE, 1);
                float oO = __shfl_xor(vO, 1);
                float lo = e ? oO : vE;
                float hi = e ? vO : oE;
                int colb = w * 64 + (nf2 * 2 + e) * 16 + (q & ~1);
                float2 val = make_float2(lo, hi);
                *reinterpret_cast<float2*>(&obase[(g * 4 + r) * 256 + colb]) = val;
            }
    }
}

// ---------------- launch ----------------

extern "C" void kernel_launch(void* const* d_in, const int* in_sizes, int n_in,
                              void* d_out, int out_size, void* d_ws, size_t ws_size,
                              hipStream_t stream) {
    const float* stoch   = (const float*)d_in[0];
    const float* deter   = (const float*)d_in[1];
    const float* action  = (const float*)d_in[2];
    const float* W0      = (const float*)d_in[3];
    const float* b0      = (const float*)d_in[4];
    const float* g0      = (const float*)d_in[5];
    const float* norm_w  = (const float*)d_in[6];
    const float* W_in    = (const float*)d_in[7];
    const float* b_in    = (const float*)d_in[8];
    const float* W_out   = (const float*)d_in[9];
    const float* b_out   = (const float*)d_in[10];
    const float* W_skip  = (const float*)d_in[11];
    const float* b_skip  = (const float*)d_in[12];
    const float* log_dec = (const float*)d_in[13];
    const float* onw     = (const float*)d_in[14];
    float* out = (float*)d_out;

    unsigned short* A0bf    = (unsigned short*)d_ws;                  // NB*KIN
    unsigned short* W0bf    = A0bf + (size_t)NB * KIN;                // 256*KIN
    unsigned short* Winbf   = W0bf + (size_t)256 * KIN;               // NL*65536
    unsigned short* Woutbf  = Winbf + (size_t)NL * 65536;
    unsigned short* Wskipbf = Woutbf + (size_t)NL * 65536;
    float* hbuf = (float*)(Wskipbf + (size_t)NL * 65536);             // NB*256
    float* ntok = hbuf + (size_t)NB * 256;                            // NB*256

    k_cast<<<512, 256, 0, stream>>>(W0, W0bf, 256 * KIN);
    k_cast<<<512, 256, 0, stream>>>(W_in, Winbf, NL * 65536);
    k_cast<<<512, 256, 0, stream>>>(W_out, Woutbf, NL * 65536);
    k_cast<<<512, 256, 0, stream>>>(W_skip, Wskipbf, NL * 65536);
    k_build_a0<<<2048, 256, 0, stream>>>(stoch, action, A0bf);

    k_gemm_h<<<dim3(NB / 128, 4), 256, 0, stream>>>(A0bf, W0bf, b0, hbuf);
    k_h_norm<<<NB / 4, 256, 0, stream>>>(hbuf, g0, ntok);

    k_mega<<<1024, 256, 0, stream>>>(deter, ntok, Winbf, Woutbf, Wskipbf,
                                     norm_w, b_in, b_out, b_skip, log_dec, onw, out);
}

// Round 5
// 378.092 us; speedup vs baseline: 2.1736x; 1.0380x over previous
//
#include <hip/hip_runtime.h>
#include <hip/hip_bf16.h>
#include <stdint.h>

#define NB   4096
#define NTOK 16
#define ND   256
#define NS   256
#define NL   4
#define KIN  1056
#define RMS_EPS 1e-4f

typedef float f32x4 __attribute__((ext_vector_type(4)));
typedef short s16x8 __attribute__((ext_vector_type(8)));

__device__ __forceinline__ unsigned short f2bf(float f) {
    unsigned u = __float_as_uint(f);
    u += 0x7fff + ((u >> 16) & 1);          // RNE
    return (unsigned short)(u >> 16);
}

// ---------------- prep kernels ----------------

// all 4 weight casts in one launch; dst = [W0bf][Winbf][Woutbf][Wskipbf] contiguous
__global__ __launch_bounds__(256) void k_cast4(const float* __restrict__ W0,
                                               const float* __restrict__ Wi,
                                               const float* __restrict__ Wo,
                                               const float* __restrict__ Ws,
                                               unsigned short* __restrict__ dst) {
    const int n0 = 256 * KIN;          // 270336
    const int nw = NL * 65536;         // 262144
    const int total = n0 + 3 * nw;
    for (int i = blockIdx.x * blockDim.x + threadIdx.x; i < total; i += gridDim.x * blockDim.x) {
        float v;
        if (i < n0) v = W0[i];
        else {
            int j = i - n0;
            v = (j < nw) ? Wi[j] : (j < 2 * nw ? Wo[j - nw] : Ws[j - 2 * nw]);
        }
        dst[i] = f2bf(v);
    }
}

__global__ __launch_bounds__(256) void k_build_a0(const float* __restrict__ stoch,
                                                  const float* __restrict__ act,
                                                  unsigned short* __restrict__ a0) {
    int total = NB * KIN;
    for (int i = blockIdx.x * blockDim.x + threadIdx.x; i < total; i += gridDim.x * blockDim.x) {
        int b = i / KIN, k = i - b * KIN;
        float v;
        if (k < 1024) v = stoch[b * 1024 + k];
        else { float a = act[b * 32 + (k - 1024)]; v = a / fmaxf(fabsf(a), 1.0f); }
        a0[i] = f2bf(v);
    }
}

// ---------------- input-proj GEMM (K=1056) ----------------
#define KP 40
__device__ __forceinline__ void gemm_chunked(const unsigned short* __restrict__ A,
                                             const unsigned short* __restrict__ W,
                                             int K, int m0, int n0,
                                             unsigned short* lds, f32x4 acc[4][2]) {
    const int tid = threadIdx.x;
    const int lane = tid & 63;
    const int wvid = tid >> 6;
    const int wm = wvid & 1, wn = wvid >> 1;
    const int srow = tid >> 2, skk = (tid & 3) * 8;
    const int mbase = m0 + wm * 64 + (lane & 15);
    const int koff = (lane >> 4) * 8;
    const int brow = wn * 32 + (lane & 15);
    for (int kc = 0; kc < K; kc += 32) {
        __syncthreads();
        *reinterpret_cast<s16x8*>(&lds[srow * KP + skk]) =
            *reinterpret_cast<const s16x8*>(&W[(size_t)(n0 + srow) * K + kc + skk]);
        __syncthreads();
        s16x8 a[4];
#pragma unroll
        for (int mf = 0; mf < 4; mf++)
            a[mf] = *reinterpret_cast<const s16x8*>(&A[(size_t)(mbase + mf * 16) * K + kc + koff]);
#pragma unroll
        for (int nf = 0; nf < 2; nf++) {
            s16x8 bfr = *reinterpret_cast<const s16x8*>(&lds[(brow + nf * 16) * KP + koff]);
#pragma unroll
            for (int mf = 0; mf < 4; mf++)
                acc[mf][nf] = __builtin_amdgcn_mfma_f32_16x16x32_bf16(a[mf], bfr, acc[mf][nf], 0, 0, 0);
        }
    }
}

__global__ __launch_bounds__(256) void k_gemm_h(const unsigned short* __restrict__ A0,
                                                const unsigned short* __restrict__ W0bf,
                                                const float* __restrict__ b0,
                                                float* __restrict__ h) {
    __shared__ unsigned short lds[64 * KP];
    f32x4 acc[4][2];
#pragma unroll
    for (int i = 0; i < 4; i++)
#pragma unroll
        for (int j = 0; j < 2; j++) acc[i][j] = (f32x4){0.f, 0.f, 0.f, 0.f};
    int m0 = blockIdx.x * 128, n0 = blockIdx.y * 64;
    gemm_chunked(A0, W0bf, KIN, m0, n0, lds, acc);
    int lane = threadIdx.x & 63, wvid = threadIdx.x >> 6;
    int wm = wvid & 1, wn = wvid >> 1;
    int rbase = m0 + wm * 64 + (lane >> 4) * 4;
    int cbase = n0 + wn * 32 + (lane & 15);
#pragma unroll
    for (int mf = 0; mf < 4; mf++)
#pragma unroll
        for (int nf = 0; nf < 2; nf++) {
            int col = cbase + nf * 16;
            float bb = b0[col];
#pragma unroll
            for (int r = 0; r < 4; r++)
                h[(size_t)(rbase + mf * 16 + r) * ND + col] = acc[mf][nf][r] + bb;
        }
}

// rms + silu -> ntok (contiguous fp32 [4096][256])
__global__ __launch_bounds__(256) void k_h_norm(const float* __restrict__ X,
                                                const float* __restrict__ wg,
                                                float* __restrict__ ntok) {
    int row = blockIdx.x * 4 + (threadIdx.x >> 6);
    int lane = threadIdx.x & 63;
    float4 v = reinterpret_cast<const float4*>(X)[(size_t)row * 64 + lane];
    float ss = v.x * v.x + v.y * v.y + v.z * v.z + v.w * v.w;
#pragma unroll
    for (int off = 32; off > 0; off >>= 1) ss += __shfl_xor(ss, off);
    float scale = rsqrtf(ss * (1.0f / 256.0f) + RMS_EPS);
    float4 wv = reinterpret_cast<const float4*>(wg)[lane];
    float o0 = v.x * scale * wv.x, o1 = v.y * scale * wv.y;
    float o2 = v.z * scale * wv.z, o3 = v.w * scale * wv.w;
    float4 qq;
    qq.x = o0 / (1.f + expf(-o0));
    qq.y = o1 / (1.f + expf(-o1));
    qq.z = o2 / (1.f + expf(-o2));
    qq.w = o3 / (1.f + expf(-o3));
    reinterpret_cast<float4*>(ntok)[(size_t)row * 64 + lane] = qq;
}

// ---------------- persistent mega-kernel (v2) ----------------
// 512 thr = 8 waves. Block owns 4 batch rows (M = 64 token-rows), all layers.
// Wave w owns output cols [w*32, w*32+32): tok[mf][nf] f32x4, nf in {0,1}.
//   tok[mf][nf][r] = row (mf*16 + g*4 + r), col (w*32 + nf*16 + q)
// ONE shared A-tile xs[64][264] (bf16): holds x for skip/u GEMMs, then states
// for the out GEMM (overwritten after a barrier). GEMMs accumulate into tok
// in place via MFMA's C operand -> no second accumulator array.
// Register budget: tok 32 + acc 32 + temps ~50 <= 128 -> 4 waves/SIMD,
// 2 blocks/CU (LDS 36 KB) = 16 waves/CU.

#define LSTR 264

__global__ __launch_bounds__(512, 4) void k_mega(
    const float* __restrict__ deter, const float* __restrict__ ntok,
    const unsigned short* __restrict__ Win, const unsigned short* __restrict__ Wout,
    const unsigned short* __restrict__ Wskip,
    const float* __restrict__ norm_w, const float* __restrict__ b_in,
    const float* __restrict__ b_out, const float* __restrict__ b_skip,
    const float* __restrict__ log_dec, const float* __restrict__ out_nw,
    float* __restrict__ out)
{
    __shared__ __align__(16) unsigned short xs[64 * LSTR];   // 33792 B
    __shared__ __align__(16) float red[8 * 64 + 64];         // 2304 B

    const int tid = threadIdx.x;
    const int lane = tid & 63;
    const int w = tid >> 6;          // 0..7 -> col window w*32
    const int g = lane >> 4;
    const int q = lane & 15;
    const int b0 = blockIdx.x * 4;
    const int lm16 = (lane - 16) & 63, lm32 = (lane - 32) & 63, lm48 = (lane - 48) & 63;

    f32x4 tok[4][2];
    // ---- entry: shifted deter tokens + new token ----
#pragma unroll
    for (int mf = 0; mf < 4; mf++) {
        const float* dbase = deter + (size_t)(b0 + mf) * 4096;
        const float* nbase = ntok + (size_t)(b0 + mf) * 256;
#pragma unroll
        for (int nf = 0; nf < 2; nf++) {
            int col = w * 32 + nf * 16 + q;
#pragma unroll
            for (int r = 0; r < 4; r++) {
                int t = g * 4 + r;
                tok[mf][nf][r] = (t < 15) ? dbase[(t + 1) * 256 + col] : nbase[col];
            }
        }
    }

    float scale[4][4];

    auto rms_scale = [&]() {
#pragma unroll
        for (int mf = 0; mf < 4; mf++) {
            f32x4 p;
#pragma unroll
            for (int r = 0; r < 4; r++)
                p[r] = tok[mf][0][r] * tok[mf][0][r] + tok[mf][1][r] * tok[mf][1][r];
#pragma unroll
            for (int mask = 1; mask < 16; mask <<= 1) {
#pragma unroll
                for (int r = 0; r < 4; r++) p[r] += __shfl_xor(p[r], mask);
            }
            if (q == 0) *reinterpret_cast<f32x4*>(&red[w * 64 + mf * 16 + g * 4]) = p;
        }
        __syncthreads();
        if (tid < 64) {
            float s = 0.f;
#pragma unroll
            for (int j = 0; j < 8; j++) s += red[j * 64 + tid];
            red[512 + tid] = rsqrtf(s * (1.0f / 256.0f) + RMS_EPS);
        }
        __syncthreads();
#pragma unroll
        for (int mf = 0; mf < 4; mf++) {
            f32x4 sc = *reinterpret_cast<const f32x4*>(&red[512 + mf * 16 + g * 4]);
#pragma unroll
            for (int r = 0; r < 4; r++) scale[mf][r] = sc[r];
        }
    };

    // GEMM over the shared A-tile; accumulates into acc IN PLACE.
    auto gemm = [&](const unsigned short* __restrict__ Bmat, f32x4 acc[4][2]) {
        const unsigned short* bp = Bmat + (size_t)(w * 32 + q) * 256 + g * 8;
        const unsigned short* ap = xs + q * LSTR + g * 8;
#pragma unroll 2
        for (int kc = 0; kc < 256; kc += 32) {
            s16x8 bw0 = *reinterpret_cast<const s16x8*>(bp + kc);
            s16x8 bw1 = *reinterpret_cast<const s16x8*>(bp + 16 * 256 + kc);
#pragma unroll
            for (int mf = 0; mf < 4; mf++) {
                s16x8 a = *reinterpret_cast<const s16x8*>(ap + mf * (16 * LSTR) + kc);
                acc[mf][0] = __builtin_amdgcn_mfma_f32_16x16x32_bf16(a, bw0, acc[mf][0], 0, 0, 0);
                acc[mf][1] = __builtin_amdgcn_mfma_f32_16x16x32_bf16(a, bw1, acc[mf][1], 0, 0, 0);
            }
        }
    };

    for (int l = 0; l < NL; l++) {
        const unsigned short* Wi = Win + (size_t)l * 65536;
        const unsigned short* Wo = Wout + (size_t)l * 65536;
        const unsigned short* Ws = Wskip + (size_t)l * 65536;
        float nw[2], bi[2], dec[2], bo[2];
#pragma unroll
        for (int nf = 0; nf < 2; nf++) {
            int col = w * 32 + nf * 16 + q;
            nw[nf] = norm_w[l * 256 + col];
            bi[nf] = b_in[l * 256 + col];
            dec[nf] = 1.f / (1.f + expf(-log_dec[l * 256 + col]));
            bo[nf] = b_out[l * 256 + col] + b_skip[l * 256 + col];
        }

        rms_scale();   // 2 barriers: also protects xs from previous layer's reads
        // x = rms(tok)*nw -> xs  (direct b16 stores, no shuffles; 2-way banks = free)
#pragma unroll
        for (int mf = 0; mf < 4; mf++)
#pragma unroll
            for (int r = 0; r < 4; r++) {
                int m = mf * 16 + g * 4 + r;
#pragma unroll
                for (int nf = 0; nf < 2; nf++)
                    xs[m * LSTR + w * 32 + nf * 16 + q] = f2bf(tok[mf][nf][r] * scale[mf][r] * nw[nf]);
            }
        __syncthreads();

        // skip GEMM: tok += x @ Wskip^T   (in-place C accumulate)
        gemm(Ws, tok);

        // u GEMM: acc = x @ Win^T
        f32x4 acc[4][2];
#pragma unroll
        for (int i = 0; i < 4; i++)
#pragma unroll
            for (int j = 0; j < 2; j++) acc[i][j] = (f32x4){0.f, 0.f, 0.f, 0.f};
        gemm(Wi, acc);

        // bias + in-register decay scan over t = g*4+r
#pragma unroll
        for (int mf = 0; mf < 4; mf++)
#pragma unroll
            for (int nf = 0; nf < 2; nf++) {
                float d1 = dec[nf], dd2 = d1 * d1, dd3 = dd2 * d1, dd4 = dd2 * dd2, dd8 = dd4 * dd4;
                f32x4& u = acc[mf][nf];
                float s0 = u[0] + bi[nf];
                float s1 = u[1] + bi[nf] + d1 * s0;
                float s2 = u[2] + bi[nf] + d1 * s1;
                float s3 = u[3] + bi[nf] + d1 * s2;
                float Q = s3;
                float q1 = __shfl(Q, lm16); q1 = (g >= 1) ? q1 : 0.f;
                float q2 = __shfl(Q, lm32); q2 = (g >= 2) ? q2 : 0.f;
                float q3 = __shfl(Q, lm48); q3 = (g >= 3) ? q3 : 0.f;
                float carry = q1 + dd4 * q2 + dd8 * q3;
                u[0] = s0 + d1 * carry;
                u[1] = s1 + dd2 * carry;
                u[2] = s2 + dd3 * carry;
                u[3] = s3 + dd4 * carry;
            }

        __syncthreads();   // all waves done reading xs (skip+u GEMMs)
        // states -> xs (overwrite)
#pragma unroll
        for (int mf = 0; mf < 4; mf++)
#pragma unroll
            for (int r = 0; r < 4; r++) {
                int m = mf * 16 + g * 4 + r;
#pragma unroll
                for (int nf = 0; nf < 2; nf++)
                    xs[m * LSTR + w * 32 + nf * 16 + q] = f2bf(acc[mf][nf][r]);
            }
        __syncthreads();

        // out GEMM: tok += states @ Wout^T  (in place), then biases
        gemm(Wo, tok);
#pragma unroll
        for (int mf = 0; mf < 4; mf++)
#pragma unroll
            for (int nf = 0; nf < 2; nf++)
#pragma unroll
                for (int r = 0; r < 4; r++)
                    tok[mf][nf][r] += bo[nf];
    }

    // final rmsnorm -> fp32 out
    rms_scale();
    float onw[2];
#pragma unroll
    for (int nf = 0; nf < 2; nf++) onw[nf] = out_nw[w * 32 + nf * 16 + q];
#pragma unroll
    for (int mf = 0; mf < 4; mf++) {
        float* obase = out + (size_t)(b0 + mf) * 4096;
#pragma unroll
        for (int r = 0; r < 4; r++)
#pragma unroll
            for (int nf = 0; nf < 2; nf++)
                obase[(g * 4 + r) * 256 + w * 32 + nf * 16 + q] =
                    tok[mf][nf][r] * scale[mf][r] * onw[nf];
    }
}

// ---------------- launch ----------------

extern "C" void kernel_launch(void* const* d_in, const int* in_sizes, int n_in,
                              void* d_out, int out_size, void* d_ws, size_t ws_size,
                              hipStream_t stream) {
    const float* stoch   = (const float*)d_in[0];
    const float* deter   = (const float*)d_in[1];
    const float* action  = (const float*)d_in[2];
    const float* W0      = (const float*)d_in[3];
    const float* b0      = (const float*)d_in[4];
    const float* g0      = (const float*)d_in[5];
    const float* norm_w  = (const float*)d_in[6];
    const float* W_in    = (const float*)d_in[7];
    const float* b_in    = (const float*)d_in[8];
    const float* W_out   = (const float*)d_in[9];
    const float* b_out   = (const float*)d_in[10];
    const float* W_skip  = (const float*)d_in[11];
    const float* b_skip  = (const float*)d_in[12];
    const float* log_dec = (const float*)d_in[13];
    const float* onw     = (const float*)d_in[14];
    float* out = (float*)d_out;

    unsigned short* A0bf    = (unsigned short*)d_ws;                  // NB*KIN
    unsigned short* W0bf    = A0bf + (size_t)NB * KIN;                // 256*KIN
    unsigned short* Winbf   = W0bf + (size_t)256 * KIN;               // NL*65536
    unsigned short* Woutbf  = Winbf + (size_t)NL * 65536;
    unsigned short* Wskipbf = Woutbf + (size_t)NL * 65536;
    float* hbuf = (float*)(Wskipbf + (size_t)NL * 65536);             // NB*256
    float* ntok = hbuf + (size_t)NB * 256;                            // NB*256

    k_cast4<<<1024, 256, 0, stream>>>(W0, W_in, W_out, W_skip, W0bf);
    k_build_a0<<<2048, 256, 0, stream>>>(stoch, action, A0bf);

    k_gemm_h<<<dim3(NB / 128, 4), 256, 0, stream>>>(A0bf, W0bf, b0, hbuf);
    k_h_norm<<<NB / 4, 256, 0, stream>>>(hbuf, g0, ntok);

    k_mega<<<1024, 512, 0, stream>>>(deter, ntok, Winbf, Woutbf, Wskipbf,
                                     norm_w, b_in, b_out, b_skip, log_dec, onw, out);
}